// Round 9
// baseline (367.834 us; speedup 1.0000x reference)
//
#include <hip/hip_runtime.h>
#include <math.h>

#define B_ 4
#define N_ 4096
#define E_ 131072
#define ET_ (E_ + N_)   /* 135168 edges incl. self-loops */
#define H_ 4
#define HD_ 256
#define C_ 6

typedef short  s16x8  __attribute__((ext_vector_type(8)));
typedef __bf16 bf16x8 __attribute__((ext_vector_type(8)));
typedef float  f32x4  __attribute__((ext_vector_type(4)));

__device__ inline unsigned short f2bf(float f){
  unsigned u = __builtin_bit_cast(unsigned, f);
  return (unsigned short)((u + 0x7FFFu + ((u >> 16) & 1u)) >> 16);
}
__device__ inline float bf2f(unsigned short s){
  unsigned u = ((unsigned)s) << 16;
  return __builtin_bit_cast(float, u);
}
__device__ inline float bflo(unsigned u){ return __builtin_bit_cast(float, u << 16); }
__device__ inline float bfhi(unsigned u){ return __builtin_bit_cast(float, u & 0xFFFF0000u); }
__device__ inline void split2(float f, short& hi, short& lo){
  unsigned short h = f2bf(f);
  hi = (short)h;
  lo = (short)f2bf(f - bf2f(h));
}
__device__ inline f32x4 mfma_bf16(s16x8 a, s16x8 b, f32x4 c){
  return __builtin_amdgcn_mfma_f32_16x16x32_bf16(
      __builtin_bit_cast(bf16x8, a), __builtin_bit_cast(bf16x8, b), c, 0, 0, 0);
}

// ---------------- CSR build (counting sort by dst) ----------------
__global__ void k_count(const int* __restrict__ ei, int* __restrict__ counts){
  int idx = blockIdx.x*256 + threadIdx.x;
  if (idx >= B_*ET_) return;
  int b = idx / ET_, i = idx - b*ET_;
  int dst = (i < E_) ? ei[b*2*E_ + E_ + i] : (i - E_);
  atomicAdd(&counts[b*N_ + dst], 1);
}

__global__ void k_scan(const int* __restrict__ counts, int* __restrict__ offs){
  __shared__ int lds[1024];
  int b = blockIdx.x, t = threadIdx.x;
  int c[4]; int tot = 0;
  #pragma unroll
  for (int j=0;j<4;j++){ c[j] = counts[b*N_ + t*4 + j]; tot += c[j]; }
  lds[t] = tot; __syncthreads();
  for (int off=1; off<1024; off<<=1){
    int u = (t>=off) ? lds[t-off] : 0;
    __syncthreads();
    lds[t] += u;
    __syncthreads();
  }
  int excl = lds[t] - tot;
  int o = excl;
  #pragma unroll
  for (int j=0;j<4;j++){ offs[b*(N_+1) + t*4 + j] = o; o += c[j]; }
  if (t==1023) offs[b*(N_+1) + N_] = o;
}

__global__ void k_scatter(const int* __restrict__ ei, const int* __restrict__ offs,
                          int* __restrict__ cursor, unsigned short* __restrict__ srcs){
  int idx = blockIdx.x*256 + threadIdx.x;
  if (idx >= B_*ET_) return;
  int b = idx / ET_, i = idx - b*ET_;
  int src, dst;
  if (i < E_){ src = ei[b*2*E_ + i]; dst = ei[b*2*E_ + E_ + i]; }
  else { src = i - E_; dst = src; }
  int pos = offs[b*(N_+1) + dst] + atomicAdd(&cursor[b*N_ + dst], 1);
  srcs[b*ET_ + pos] = (unsigned short)src;
}

// split + transpose W[K,NC] -> Wt[NC,K] (hi,lo)
__global__ void k_splitT(const float* __restrict__ w, short* __restrict__ hit,
                         short* __restrict__ lot, int K, int NC){
  int idx = blockIdx.x*256 + threadIdx.x;
  if (idx >= K*NC) return;
  int nn = idx / K, kk = idx - nn*K;
  float f = w[(size_t)kk*NC + nn];
  short h, l; split2(f, h, l);
  hit[idx] = h; lot[idx] = l;
}

// ---------------- register-direct split-bf16 MFMA GEMM (no LDS) ----------------
// Each wave owns a 64x64 output tile; A/B fragments are loaded DIRECTLY from
// global (frag load = 16 lanes x 16B over 16 rows at one 64B-aligned k-chunk =
// 4 lanes/line, same line efficiency as coalesced dwordx4; B rows L1-resident).
// No LDS, no barriers. 1-deep register double buffer on raw loads.
// Fused attn epilogue: wave covers a full 64-col head -> plain stores.
template<int K, bool AFP32, int H>
__global__ __launch_bounds__(256,1) void k_gemm_r(const float* __restrict__ Af,
    const short* __restrict__ Ah_, const short* __restrict__ Al_,
    const short* __restrict__ Bh_, const short* __restrict__ Bl_,
    unsigned short* __restrict__ Ob, int NC,
    const float* __restrict__ atts, const float* __restrict__ attd,
    float* __restrict__ a_s, float* __restrict__ a_d){
  int t = threadIdx.x;
  int w = t >> 6, l = t & 63, g = l >> 4, li = l & 15;
  int m0 = (blockIdx.x*4 + w)*64;        // wave-private 64-row strip
  int n0 = blockIdx.y*64;                // 64-col strip == one head
  int head = blockIdx.y;

  // per-lane row offsets (32-bit; saddr+voffset addressing)
  size_t offB[4], offA[4];
  #pragma unroll
  for (int ni=0;ni<4;ni++) offB[ni] = (size_t)(n0 + ni*16 + li)*K + g*8;
  #pragma unroll
  for (int mi=0;mi<4;mi++) offA[mi] = (size_t)(m0 + mi*16 + li)*K + g*8;

  f32x4 acc[4][4];
  #pragma unroll
  for (int mi=0;mi<4;mi++)
    #pragma unroll
    for (int ni=0;ni<4;ni++) acc[mi][ni] = f32x4{0.f,0.f,0.f,0.f};

  s16x8 bhc[4], blc[4], bhn[4], bln[4];
  s16x8 ahc[4], alc[4], ahn[4], aln[4];
  float4 a0c[4], a1c[4], a0n[4], a1n[4];

  auto loadB = [&](int k0, s16x8* bh, s16x8* bl){
    #pragma unroll
    for (int ni=0;ni<4;ni++){
      bh[ni] = *reinterpret_cast<const s16x8*>(Bh_ + offB[ni] + k0);
      bl[ni] = *reinterpret_cast<const s16x8*>(Bl_ + offB[ni] + k0);
    }
  };
  auto loadA = [&](int k0, s16x8* ah, s16x8* al, float4* a0, float4* a1){
    #pragma unroll
    for (int mi=0;mi<4;mi++){
      if constexpr (AFP32){
        const float* ap = Af + offA[mi] + k0;
        a0[mi] = *reinterpret_cast<const float4*>(ap);
        a1[mi] = *reinterpret_cast<const float4*>(ap+4);
      } else {
        ah[mi] = *reinterpret_cast<const s16x8*>(Ah_ + offA[mi] + k0);
        al[mi] = *reinterpret_cast<const s16x8*>(Al_ + offA[mi] + k0);
      }
    }
  };

  loadB(0, bhc, blc);
  loadA(0, ahc, alc, a0c, a1c);

  for (int k0 = 0; k0 < K; k0 += 32){
    bool more = (k0 + 32 < K);
    if (more){                            // issue next-slice loads; land under MFMAs
      loadB(k0+32, bhn, bln);
      loadA(k0+32, ahn, aln, a0n, a1n);
    }
    s16x8 ah[4], al[4];
    #pragma unroll
    for (int mi=0;mi<4;mi++){
      if constexpr (AFP32){
        float fv[8] = {a0c[mi].x,a0c[mi].y,a0c[mi].z,a0c[mi].w,
                       a1c[mi].x,a1c[mi].y,a1c[mi].z,a1c[mi].w};
        #pragma unroll
        for (int j=0;j<8;j++){ short hi,lo; split2(fv[j],hi,lo); ah[mi][j]=hi; al[mi][j]=lo; }
      } else { ah[mi] = ahc[mi]; al[mi] = alc[mi]; }
    }
    #pragma unroll
    for (int mi=0;mi<4;mi++)
      #pragma unroll
      for (int ni=0;ni<4;ni++){
        acc[mi][ni] = mfma_bf16(ah[mi], bhc[ni], acc[mi][ni]);
        acc[mi][ni] = mfma_bf16(ah[mi], blc[ni], acc[mi][ni]);
        acc[mi][ni] = mfma_bf16(al[mi], bhc[ni], acc[mi][ni]);
      }
    if (more){
      #pragma unroll
      for (int ni=0;ni<4;ni++){ bhc[ni]=bhn[ni]; blc[ni]=bln[ni]; }
      #pragma unroll
      for (int mi=0;mi<4;mi++){
        if constexpr (AFP32){ a0c[mi]=a0n[mi]; a1c[mi]=a1n[mi]; }
        else { ahc[mi]=ahn[mi]; alc[mi]=aln[mi]; }
      }
    }
  }

  // C/D layout: col = lane&15, row = 4*(lane>>4) + reg
  float attsv[4], attdv[4];
  #pragma unroll
  for (int ni=0;ni<4;ni++){
    int col = n0 + ni*16 + li;
    attsv[ni] = atts[col]; attdv[ni] = attd[col];
  }
  #pragma unroll
  for (int mi=0;mi<4;mi++){
    #pragma unroll
    for (int j=0;j<4;j++){
      int row = m0 + mi*16 + 4*g + j;
      float sa = acc[mi][0][j]*attsv[0] + acc[mi][1][j]*attsv[1]
               + acc[mi][2][j]*attsv[2] + acc[mi][3][j]*attsv[3];
      float sd = acc[mi][0][j]*attdv[0] + acc[mi][1][j]*attdv[1]
               + acc[mi][2][j]*attdv[2] + acc[mi][3][j]*attdv[3];
      #pragma unroll
      for (int m=1;m<16;m<<=1){ sa += __shfl_xor(sa,m,64); sd += __shfl_xor(sd,m,64); }
      if (li == 0){
        a_s[(size_t)row*H + head] = sa;   // single contributor -> plain store
        a_d[(size_t)row*H + head] = sd;
      }
      #pragma unroll
      for (int ni=0;ni<4;ni++){
        int col = n0 + ni*16 + li;
        Ob[(size_t)row*NC + col] = f2bf(acc[mi][ni][j]);
      }
    }
  }
}

// ---------------- pull-mode edge-softmax aggregation (multi-edge waves) ----------------
template<int HD, int H, bool ELU, bool SPLIT>
__global__ __launch_bounds__(256) void k_aggr(const unsigned short* __restrict__ h,
    const float* __restrict__ a_s, const float* __restrict__ a_d,
    const unsigned short* __restrict__ srcs, const int* __restrict__ offs,
    const float* __restrict__ bias, float* __restrict__ outf,
    short* __restrict__ outh, short* __restrict__ outl){
  constexpr int EPW = (HD==256) ? 2 : 4;   // edges per wave
  constexpr int LPE = 64/EPW;              // lanes per edge: 32 or 16
  constexpr int CPL = HD/LPE;              // cols per lane: 8 or 4
  constexpr int NP  = 4*EPW;               // edge slots per block: 8 or 16
  __shared__ float accL[NP][HD];
  __shared__ float psumL[NP][H];
  int ng = blockIdx.x;                     // b*N + n
  int b = ng >> 12, n = ng & (N_-1);
  int t = threadIdx.x;
  int w = t >> 6, l = t & 63;
  int sub = l / LPE, hl = l % LPE;
  int slot = w*EPW + sub;
  int st = offs[b*(N_+1)+n], en = offs[b*(N_+1)+n+1];
  const unsigned short* sp = &srcs[(size_t)b*ET_];
  const unsigned short* hb = &h[(size_t)b*N_*HD];
  const float* asb = &a_s[(size_t)b*N_*H];
  int head = (H==4) ? ((hl*CPL) >> 6) : 0;
  float adv = a_d[(size_t)ng*H + head];
  float acc[CPL];
  #pragma unroll
  for (int j=0;j<CPL;j++) acc[j]=0.f;
  float psum = 0.f;

  auto ldh = [&](int s, float* dst){
    const unsigned short* p = &hb[(size_t)s*HD + hl*CPL];
    if constexpr (CPL==8){
      uint4 q = *reinterpret_cast<const uint4*>(p);
      dst[0]=bflo(q.x); dst[1]=bfhi(q.x); dst[2]=bflo(q.y); dst[3]=bfhi(q.y);
      dst[4]=bflo(q.z); dst[5]=bfhi(q.z); dst[6]=bflo(q.w); dst[7]=bfhi(q.w);
    } else {
      uint2 q = *reinterpret_cast<const uint2*>(p);
      dst[0]=bflo(q.x); dst[1]=bfhi(q.x); dst[2]=bflo(q.y); dst[3]=bfhi(q.y);
    }
  };

  int i  = st + slot;
  int s0 = (i      < en) ? (int)sp[i]      : 0;
  int s1 = (i+NP   < en) ? (int)sp[i+NP]   : 0;
  float hv[CPL], hn[CPL], asv, asn;
  ldh(s0, hv); asv = asb[s0*H + head];

  while (i < en){
    int s2 = (i+2*NP < en) ? (int)sp[i+2*NP] : 0;   // prefetch 2 ahead
    ldh(s1, hn); asn = asb[s1*H + head];            // issue next slot loads
    float e = asv + adv;                            // compute current edge
    e = fmaxf(e, 0.2f*e);                           // leaky_relu
    float p = __expf(e);
    #pragma unroll
    for (int j=0;j<CPL;j++) acc[j] = fmaf(p, hv[j], acc[j]);
    psum += p;
    #pragma unroll
    for (int j=0;j<CPL;j++) hv[j] = hn[j];
    asv = asn; s1 = s2; i += NP;
  }

  #pragma unroll
  for (int j=0;j<CPL;j+=4)
    *reinterpret_cast<float4*>(&accL[slot][hl*CPL+j]) =
        make_float4(acc[j],acc[j+1],acc[j+2],acc[j+3]);
  if constexpr (H==4){ if ((hl & 7)==0) psumL[slot][hl>>3] = psum; }
  else               { if (hl == 0)     psumL[slot][0]     = psum; }
  __syncthreads();
  if (t < HD){
    float a = 0.f;
    #pragma unroll
    for (int k=0;k<NP;k++) a += accL[k][t];
    int h2 = (H==4) ? (t>>6) : 0;
    float ps = 0.f;
    #pragma unroll
    for (int k=0;k<NP;k++) ps += psumL[k][h2];
    float val = a/(ps + 1e-16f) + bias[t];
    if (ELU) val = val > 0.f ? val : expm1f(val);
    size_t idx = (size_t)ng*HD + t;
    if (SPLIT){ short hh, ll; split2(val, hh, ll); outh[idx]=hh; outl[idx]=ll; }
    else outf[idx] = val;
  }
}

// ---------------- node-mean reduction ----------------
__global__ void k_reduce(const float* __restrict__ x3, float* __restrict__ embed){
  __shared__ float red[256];
  int bid = blockIdx.x; int b = bid>>4, chunk = bid & 15;
  int t = threadIdx.x; int col = t & 63, q = t>>6;
  float s = 0.f;
  int r0 = chunk*256 + q*64;
  const float* p = &x3[((size_t)b*N_ + r0)*64 + col];
  for (int j=0;j<64;j++) s += p[(size_t)j*64];
  red[t]=s; __syncthreads();
  if (t<64){
    float v = red[t]+red[t+64]+red[t+128]+red[t+192];
    atomicAdd(&embed[b*64+t], v);
  }
}

// ---------------- classifier + log_softmax + loss + argmax ----------------
__global__ void k_final(const float* __restrict__ embed, const float* __restrict__ Wc,
                        const float* __restrict__ bc, const int* __restrict__ labels,
                        float* __restrict__ out){
  __shared__ float lg[B_][C_];
  __shared__ float lossv[B_];
  int t = threadIdx.x;
  if (t < B_*C_){
    int b = t / C_, c = t - b*C_;
    float s = 0.f;
    for (int k=0;k<64;k++) s += embed[b*64+k]*Wc[k*C_+c];
    lg[b][c] = s*(1.0f/N_) + bc[c];
  }
  __syncthreads();
  if (t < B_){
    int b = t;
    float mx = lg[b][0]; int pred = 0;
    for (int c=1;c<C_;c++) if (lg[b][c] > mx){ mx = lg[b][c]; pred = c; }
    float se = 0.f;
    for (int c=0;c<C_;c++) se += expf(lg[b][c]-mx);
    float lse = mx + logf(se);
    int lab = labels[b];
    lossv[b] = lse - lg[b][lab];
    out[b]      = (float)pred;
    out[B_+b]   = (float)lab;
  }
  __syncthreads();
  if (t==0) out[8] = 0.25f*(lossv[0]+lossv[1]+lossv[2]+lossv[3]);
}

extern "C" void kernel_launch(void* const* d_in, const int* in_sizes, int n_in,
                              void* d_out, int out_size, void* d_ws, size_t ws_size,
                              hipStream_t stream){
  const float* x0     = (const float*)d_in[0];
  const int*   labels = (const int*)d_in[1];
  const int*   ei     = (const int*)d_in[2];
  const float* W1=(const float*)d_in[3],  *as1=(const float*)d_in[4],
             *ad1=(const float*)d_in[5],  *b1 =(const float*)d_in[6];
  const float* W2=(const float*)d_in[7],  *as2=(const float*)d_in[8],
             *ad2=(const float*)d_in[9],  *b2 =(const float*)d_in[10];
  const float* W3=(const float*)d_in[11], *as3=(const float*)d_in[12],
             *ad3=(const float*)d_in[13], *b3 =(const float*)d_in[14];
  const float* Wc=(const float*)d_in[15], *bc =(const float*)d_in[16];
  float* out = (float*)d_out;

  char* ws = (char*)d_ws;
  size_t off = 0;
  auto alloc = [&](size_t bytes)->void*{ void* p = ws + off; off += (bytes + 255) & ~(size_t)255; return p; };
  unsigned short* hbuf = (unsigned short*)alloc((size_t)B_*N_*HD_*2); // GEMM out, bf16
  float* xcur3  = (float*)alloc((size_t)B_*N_*64*4);     // layer-3 aggr out (fp32)
  int*   counts = (int*)alloc((size_t)B_*N_*4);
  int*   cursor = (int*)alloc((size_t)B_*N_*4);
  int*   offs   = (int*)alloc((size_t)B_*(N_+1)*4);
  unsigned short* srcs = (unsigned short*)alloc((size_t)B_*ET_*2);
  float* embed  = (float*)alloc((size_t)B_*64*4);
  float* a_s1   = (float*)alloc((size_t)B_*N_*H_*4);     // zeroed block start
  float* a_d1   = (float*)alloc((size_t)B_*N_*H_*4);
  float* a_s2   = (float*)alloc((size_t)B_*N_*H_*4);
  float* a_d2   = (float*)alloc((size_t)B_*N_*H_*4);
  float* a_s3   = (float*)alloc((size_t)B_*N_*4);
  float* a_d3   = (float*)alloc((size_t)B_*N_*4);
  size_t zend   = off;                                   // zeroed block end
  short* Ah     = (short*)alloc((size_t)B_*N_*HD_*2);    // split aggr out (layers 2-3 A)
  short* Al     = (short*)alloc((size_t)B_*N_*HD_*2);
  short* Wht    = (short*)alloc((size_t)768*256*2);      // split W^T (max)
  short* Wlt    = (short*)alloc((size_t)768*256*2);

  hipMemsetAsync(counts, 0, (size_t)B_*N_*4*2, stream);            // counts+cursor
  hipMemsetAsync(embed,  0, zend - ((char*)embed - ws), stream);   // embed + a_s/a_d x3

  int nb = (B_*ET_ + 255)/256;
  k_count  <<<nb, 256, 0, stream>>>(ei, counts);
  k_scan   <<<B_, 1024, 0, stream>>>(counts, offs);
  k_scatter<<<nb, 256, 0, stream>>>(ei, offs, cursor, srcs);

  // ---- layer 1: 768 -> 4x64, concat, elu (A = x0 fp32, split in-register) ----
  {
    k_splitT<<<(768*256+255)/256, 256, 0, stream>>>(W1, Wht, Wlt, 768, 256);
    k_gemm_r<768,true,4><<<dim3(B_*N_/256, 4), 256, 0, stream>>>(x0, nullptr, nullptr,
        Wht, Wlt, hbuf, 256, as1, ad1, a_s1, a_d1);
    k_aggr<256,4,true,true><<<B_*N_, 256, 0, stream>>>(hbuf, a_s1, a_d1, srcs, offs, b1,
                                                       nullptr, Ah, Al);
  }
  // ---- layer 2: 256 -> 4x64, concat, elu ----
  {
    k_splitT<<<(256*256+255)/256, 256, 0, stream>>>(W2, Wht, Wlt, 256, 256);
    k_gemm_r<256,false,4><<<dim3(B_*N_/256, 4), 256, 0, stream>>>(nullptr, Ah, Al,
        Wht, Wlt, hbuf, 256, as2, ad2, a_s2, a_d2);
    k_aggr<256,4,true,true><<<B_*N_, 256, 0, stream>>>(hbuf, a_s2, a_d2, srcs, offs, b2,
                                                       nullptr, Ah, Al);
  }
  // ---- layer 3: 256 -> 64, 1 head, mean(=identity), no elu ----
  {
    k_splitT<<<(256*64+255)/256, 256, 0, stream>>>(W3, Wht, Wlt, 256, 64);
    k_gemm_r<256,false,1><<<dim3(B_*N_/256, 1), 256, 0, stream>>>(nullptr, Ah, Al,
        Wht, Wlt, hbuf, 64, as3, ad3, a_s3, a_d3);
    k_aggr<64,1,false,false><<<B_*N_, 256, 0, stream>>>(hbuf, a_s3, a_d3, srcs, offs, b3,
                                                        xcur3, nullptr, nullptr);
  }

  k_reduce<<<B_*16, 256, 0, stream>>>(xcur3, embed);
  k_final <<<1, 64, 0, stream>>>(embed, Wc, bc, labels, out);
}